// Round 3
// baseline (217.532 us; speedup 1.0000x reference)
//
#include <hip/hip_runtime.h>

#define GAMMA 0.1f
#define MIN_R 0.1f

// Binned-scatter parameters
#define NR 4096                 // nodes per range
#define S3 (3 * NR)             // floats per LDS acc slab (48 KB)
#define QN 3584                 // LDS queue entries (14 KB)
#define WIN 4096                // edges scanned per window (1024 thr * 4)
#define NTHR 1024
#define DRAIN_AT 3000

__device__ __forceinline__ void lj_accum(unsigned pk, const float* __restrict__ x,
                                         int lo, float* __restrict__ acc) {
    int s = (int)(pk & 0x1FFFFu);        // 17-bit src node
    int u = (int)(pk >> 17);             // 12-bit local dst index
    int d = lo + u;
    float dx = x[3 * d + 0] - x[3 * s + 0];
    float dy = x[3 * d + 1] - x[3 * s + 1];
    float dz = x[3 * d + 2] - x[3 * s + 2];
    float r2 = dx * dx + dy * dy + dz * dz;
    float r = sqrtf(r2);
    float inv_norm = 1.0f / fmaxf(r, 1e-12f);
    float rc = fmaxf(r, MIN_R);
    float s1 = 1.0f / rc;                // RC = 1
    float s2 = s1 * s1;
    float s6 = s2 * s2 * s2;
    float F = 4.0f * s6 * (12.0f * s6 - 6.0f) * s1;
    float sc = F * inv_norm;
    atomicAdd(&acc[3 * u + 0], sc * dx);
    atomicAdd(&acc[3 * u + 1], sc * dy);
    atomicAdd(&acc[3 * u + 2], sc * dz);
}

// grid = (bpr, R). Block (b, r): scan edge slice b; ballot-compact in-range
// edges into an LDS queue; drain densely; dump 48 KB partial slab to ws.
__global__ __launch_bounds__(NTHR) void edge_bin_kernel(
    const float* __restrict__ x,
    const int* __restrict__ src,
    const int* __restrict__ dst,
    float* __restrict__ ws,
    int n_edges, int epb)
{
    __shared__ __align__(16) float acc[S3];
    __shared__ unsigned queue[QN];
    __shared__ int qc;

    const int b = blockIdx.x;
    const int r = blockIdx.y;
    const int tid = threadIdx.x;
    const int lane = tid & 63;
    const int lo = r * NR;

    for (int i = tid; i < S3; i += NTHR) acc[i] = 0.0f;
    if (tid == 0) qc = 0;
    __syncthreads();

    const int slice_start = b * epb;                 // epb multiple of 4
    const int slice_end = min(slice_start + epb, n_edges);

    for (int w = slice_start; w < slice_end; w += WIN) {
        int base = w + tid * 4;
        int dd[4];
        bool vv[4];
        if (base + 3 < slice_end) {
            int4 t = *(const int4*)(dst + base);
            dd[0] = t.x; dd[1] = t.y; dd[2] = t.z; dd[3] = t.w;
            vv[0] = vv[1] = vv[2] = vv[3] = true;
        } else {
            #pragma unroll
            for (int k = 0; k < 4; ++k) {
                int e = base + k;
                vv[k] = (e < slice_end);
                dd[k] = vv[k] ? dst[e] : 0;
            }
        }
        #pragma unroll
        for (int k = 0; k < 4; ++k) {
            unsigned u = (unsigned)(dd[k] - lo);
            bool inr = vv[k] && (u < NR);
            unsigned long long m = __ballot(inr);
            if (m) {
                int leader = __ffsll((unsigned long long)m) - 1;
                int cnt = __popcll(m);
                int base_q = 0;
                if (lane == leader) base_q = atomicAdd(&qc, cnt);
                base_q = __shfl(base_q, leader);
                if (inr) {
                    int pos = base_q + __popcll(m & ((1ull << lane) - 1ull));
                    unsigned pk = (u << 17) | (unsigned)src[base + k];
                    if (pos < QN) queue[pos] = pk;
                    else lj_accum(pk, x, lo, acc);   // overflow fallback
                }
            }
        }
        __syncthreads();                             // pushes visible; uniform qc
        bool last = (w + WIN >= slice_end);
        int qcv = qc;
        if (qcv >= DRAIN_AT || (last && qcv > 0)) {
            int qn = min(qcv, QN);
            for (int i = tid; i < qn; i += NTHR) lj_accum(queue[i], x, lo, acc);
            __syncthreads();
            if (tid == 0) qc = 0;
            __syncthreads();
        }
    }
    __syncthreads();

    // Dump slab (coalesced float4 stores)
    float* slab = ws + (size_t)(r * gridDim.x + b) * S3;
    const float4* a4 = (const float4*)acc;
    float4* s4 = (float4*)slab;
    for (int i = tid; i < S3 / 4; i += NTHR) s4[i] = a4[i];
}

// out[g] = sum_b ws[(r*bpr+b)*S3 + j] - GAMMA*v[g]   (float4-vectorized)
__global__ void merge_kernel(const float* __restrict__ ws,
                             const float* __restrict__ v,
                             float* __restrict__ out,
                             int n_out, int bpr)
{
    int t = blockIdx.x * blockDim.x + threadIdx.x;
    int g = t * 4;
    if (g + 3 < n_out) {
        int r = g / S3;
        int j = g - r * S3;
        const float4* base = (const float4*)(ws + (size_t)r * bpr * S3 + j);
        float4 sum = make_float4(0.f, 0.f, 0.f, 0.f);
        for (int b = 0; b < bpr; ++b) {
            float4 p = base[(size_t)b * (S3 / 4)];
            sum.x += p.x; sum.y += p.y; sum.z += p.z; sum.w += p.w;
        }
        float4 vg = *(const float4*)(v + g);
        float4 o;
        o.x = sum.x - GAMMA * vg.x;
        o.y = sum.y - GAMMA * vg.y;
        o.z = sum.z - GAMMA * vg.z;
        o.w = sum.w - GAMMA * vg.w;
        *(float4*)(out + g) = o;
    } else {
        for (; g < n_out; ++g) {
            int r = g / S3;
            int j = g - r * S3;
            const float* base = ws + (size_t)r * bpr * S3 + j;
            float sum = 0.0f;
            for (int b = 0; b < bpr; ++b) sum += base[(size_t)b * S3];
            out[g] = sum - GAMMA * v[g];
        }
    }
}

// ---------------- fallback path (if ws too small) ---------------------------
__global__ void init_out_kernel(const float* __restrict__ v,
                                float* __restrict__ out, int n) {
    int i = blockIdx.x * blockDim.x + threadIdx.x;
    if (i < n) out[i] = -GAMMA * v[i];
}

__global__ void edge_atomic_kernel(const float* __restrict__ x,
                                   const int* __restrict__ src,
                                   const int* __restrict__ dst,
                                   float* __restrict__ out, int n_edges) {
    int t = blockIdx.x * blockDim.x + threadIdx.x;
    for (int e = t * 4; e < min(t * 4 + 4, n_edges); ++e) {
        int s = src[e], d = dst[e];
        float dx = x[3 * d + 0] - x[3 * s + 0];
        float dy = x[3 * d + 1] - x[3 * s + 1];
        float dz = x[3 * d + 2] - x[3 * s + 2];
        float r = sqrtf(dx * dx + dy * dy + dz * dz);
        float inv_norm = 1.0f / fmaxf(r, 1e-12f);
        float rc = fmaxf(r, MIN_R);
        float s1 = 1.0f / rc;
        float s2 = s1 * s1;
        float s6 = s2 * s2 * s2;
        float F = 4.0f * s6 * (12.0f * s6 - 6.0f) * s1;
        float sc = F * inv_norm;
        unsafeAtomicAdd(&out[3 * d + 0], sc * dx);
        unsafeAtomicAdd(&out[3 * d + 1], sc * dy);
        unsafeAtomicAdd(&out[3 * d + 2], sc * dz);
    }
}

extern "C" void kernel_launch(void* const* d_in, const int* in_sizes, int n_in,
                              void* d_out, int out_size, void* d_ws, size_t ws_size,
                              hipStream_t stream) {
    const float* x   = (const float*)d_in[0];
    const float* v   = (const float*)d_in[1];
    const int*   src = (const int*)d_in[2];
    const int*   dst = (const int*)d_in[3];
    float* out = (float*)d_out;

    const int n_out = out_size;
    const int n_nodes = out_size / 3;
    const int n_edges = in_sizes[2];
    const int R = (n_nodes + NR - 1) / NR;

    int bpr = 0;
    for (int cand : {20, 10, 5}) {
        size_t need = (size_t)R * cand * S3 * sizeof(float);
        if (need <= ws_size) { bpr = cand; break; }
    }

    if (bpr > 0) {
        int epb = ((n_edges + bpr - 1) / bpr + 3) & ~3;
        dim3 grid(bpr, R);
        edge_bin_kernel<<<grid, NTHR, 0, stream>>>(x, src, dst, (float*)d_ws,
                                                   n_edges, epb);
        int blk = 256;
        int n4 = (n_out + 3) / 4;
        merge_kernel<<<(n4 + blk - 1) / blk, blk, 0, stream>>>(
            (const float*)d_ws, v, out, n_out, bpr);
    } else {
        int blk = 256;
        init_out_kernel<<<(n_out + blk - 1) / blk, blk, 0, stream>>>(v, out, n_out);
        int n_t = (n_edges + 3) / 4;
        edge_atomic_kernel<<<(n_t + blk - 1) / blk, blk, 0, stream>>>(x, src, dst,
                                                                      out, n_edges);
    }
}

// Round 4
// 176.579 us; speedup vs baseline: 1.2319x; 1.2319x over previous
//
#include <hip/hip_runtime.h>

#define GAMMA 0.1f
#define MIN_R 0.1f

// Counting-sort-by-range parameters
#define NR 2048                 // nodes per range (power of 2)
#define LOG_NR 11
#define S3 (3 * NR)             // floats per slab / x-slice (24 KB)
#define NB 256                  // blocks for count/scatter kernels
#define THR_AC 256              // threads for count/scatter
#define THR_D 512               // threads for process kernel
#define RMAX 64                 // max ranges supported (n_nodes <= 131072)

// ---------------- phase A: per-block range histogram -------------------------
__global__ __launch_bounds__(THR_AC) void count_kernel(
    const int* __restrict__ dst, unsigned* __restrict__ counts,
    int n_edges, int epb, int R)
{
    __shared__ unsigned hist[RMAX];
    const int b = blockIdx.x, t = threadIdx.x;
    if (t < RMAX) hist[t] = 0;
    __syncthreads();
    const int s0 = b * epb;
    const int s1 = min(s0 + epb, n_edges);
    for (int base = s0 + t * 4; base < s1; base += THR_AC * 4) {
        if (base + 3 < s1) {
            int4 d4 = *(const int4*)(dst + base);
            atomicAdd(&hist[(unsigned)d4.x >> LOG_NR], 1u);
            atomicAdd(&hist[(unsigned)d4.y >> LOG_NR], 1u);
            atomicAdd(&hist[(unsigned)d4.z >> LOG_NR], 1u);
            atomicAdd(&hist[(unsigned)d4.w >> LOG_NR], 1u);
        } else {
            for (int e = base; e < s1; ++e)
                atomicAdd(&hist[(unsigned)dst[e] >> LOG_NR], 1u);
        }
    }
    __syncthreads();
    if (t < R) counts[b * R + t] = hist[t];
}

// ---------------- phase B1: per-bin exclusive scan over blocks ---------------
// grid = R blocks, NB threads. bases[b][r] = sum_{b'<b} counts[b'][r]; totals[r].
__global__ __launch_bounds__(NB) void scan_blocks_kernel(
    const unsigned* __restrict__ counts, unsigned* __restrict__ bases,
    unsigned* __restrict__ totals, int R)
{
    __shared__ unsigned s[NB];
    const int r = blockIdx.x, t = threadIdx.x;
    unsigned orig = counts[t * R + r];
    s[t] = orig;
    __syncthreads();
    for (int d = 1; d < NB; d <<= 1) {
        unsigned v = (t >= d) ? s[t - d] : 0u;
        __syncthreads();
        s[t] += v;
        __syncthreads();
    }
    bases[t * R + r] = s[t] - orig;           // exclusive
    if (t == NB - 1) totals[r] = s[t];
}

// ---------------- phase B2: exclusive scan over bins -------------------------
__global__ void scan_bins_kernel(const unsigned* __restrict__ totals,
                                 unsigned* __restrict__ offsets, int R)
{
    __shared__ unsigned tot[RMAX];
    const int t = threadIdx.x;
    if (t < R) tot[t] = totals[t];
    __syncthreads();
    if (t == 0) {
        unsigned off = 0;
        for (int r = 0; r < R; ++r) { offsets[r] = off; off += tot[r]; }
        offsets[R] = off;
    }
}

// ---------------- phase C: scatter packed edges into bins --------------------
__global__ __launch_bounds__(THR_AC) void scatter_kernel(
    const int* __restrict__ src, const int* __restrict__ dst,
    const unsigned* __restrict__ bases, const unsigned* __restrict__ offsets,
    unsigned* __restrict__ pk, int n_edges, int epb, int R)
{
    __shared__ unsigned cursor[RMAX];
    const int b = blockIdx.x, t = threadIdx.x;
    if (t < R) cursor[t] = bases[b * R + t] + offsets[t];
    __syncthreads();
    const int s0 = b * epb;
    const int s1 = min(s0 + epb, n_edges);
    for (int base = s0 + t * 4; base < s1; base += THR_AC * 4) {
        if (base + 3 < s1) {
            int4 d4 = *(const int4*)(dst + base);
            int4 s4 = *(const int4*)(src + base);
            #pragma unroll
            for (int k = 0; k < 4; ++k) {
                unsigned d = (unsigned)((k == 0) ? d4.x : (k == 1) ? d4.y : (k == 2) ? d4.z : d4.w);
                unsigned s = (unsigned)((k == 0) ? s4.x : (k == 1) ? s4.y : (k == 2) ? s4.z : s4.w);
                unsigned r = d >> LOG_NR;
                unsigned u = d & (NR - 1);
                unsigned pos = atomicAdd(&cursor[r], 1u);
                pk[pos] = (u << 17) | s;
            }
        } else {
            for (int e = base; e < s1; ++e) {
                unsigned d = (unsigned)dst[e];
                unsigned r = d >> LOG_NR;
                unsigned u = d & (NR - 1);
                unsigned pos = atomicAdd(&cursor[r], 1u);
                pk[pos] = (u << 17) | (unsigned)src[e];
            }
        }
    }
}

// ---------------- phase D: dense per-range LJ accumulate ---------------------
// grid = (bpr, R). Block (b, r): process slice of bin r, accumulate in LDS,
// dump 24 KB partial slab.
__global__ __launch_bounds__(THR_D) void process_kernel(
    const float* __restrict__ x, const unsigned* __restrict__ pk,
    const unsigned* __restrict__ offsets, float* __restrict__ slabs,
    int n_nodes, int bpr)
{
    __shared__ __align__(16) float acc[S3];
    __shared__ __align__(16) float xr[S3];
    const int b = blockIdx.x, r = blockIdx.y, t = threadIdx.x;
    const int lo = r * NR;
    const int xbase = 3 * lo;
    const int xlim = 3 * n_nodes;
    for (int i = t; i < S3; i += THR_D) {
        acc[i] = 0.0f;
        int g = xbase + i;
        xr[i] = (g < xlim) ? x[g] : 0.0f;
    }
    __syncthreads();

    const int e0 = (int)offsets[r];
    const int e1 = (int)offsets[r + 1];
    const int cnt = e1 - e0;
    const int ebp = (cnt + bpr - 1) / bpr;
    const int st = e0 + b * ebp;
    const int en = min(st + ebp, e1);

    for (int e = st + t; e < en; e += THR_D) {
        unsigned p = pk[e];
        int s = (int)(p & 0x1FFFFu);
        int u = (int)(p >> 17);
        float dx = xr[3 * u + 0] - x[3 * s + 0];
        float dy = xr[3 * u + 1] - x[3 * s + 1];
        float dz = xr[3 * u + 2] - x[3 * s + 2];
        float r2 = dx * dx + dy * dy + dz * dz;
        float rr = sqrtf(r2);
        float inv_norm = 1.0f / fmaxf(rr, 1e-12f);
        float rc = fmaxf(rr, MIN_R);
        float s1 = 1.0f / rc;                 // RC = 1
        float s2 = s1 * s1;
        float s6 = s2 * s2 * s2;
        float F = 4.0f * s6 * (12.0f * s6 - 6.0f) * s1;
        float sc = F * inv_norm;
        atomicAdd(&acc[3 * u + 0], sc * dx);
        atomicAdd(&acc[3 * u + 1], sc * dy);
        atomicAdd(&acc[3 * u + 2], sc * dz);
    }
    __syncthreads();

    float* slab = slabs + (size_t)(r * bpr + b) * S3;
    const float4* a4 = (const float4*)acc;
    float4* s4 = (float4*)slab;
    for (int i = t; i < S3 / 4; i += THR_D) s4[i] = a4[i];
}

// ---------------- phase E: merge slabs + fuse -gamma*v -----------------------
__global__ void merge_kernel(const float* __restrict__ slabs,
                             const float* __restrict__ v,
                             float* __restrict__ out,
                             int n_out, int bpr)
{
    int t = blockIdx.x * blockDim.x + threadIdx.x;
    int g = t * 4;
    if (g + 3 < n_out) {
        int r = g / S3;
        int j = g - r * S3;
        const float4* base = (const float4*)(slabs + (size_t)r * bpr * S3 + j);
        float4 sum = make_float4(0.f, 0.f, 0.f, 0.f);
        for (int b = 0; b < bpr; ++b) {
            float4 p = base[(size_t)b * (S3 / 4)];
            sum.x += p.x; sum.y += p.y; sum.z += p.z; sum.w += p.w;
        }
        float4 vg = *(const float4*)(v + g);
        float4 o;
        o.x = sum.x - GAMMA * vg.x;
        o.y = sum.y - GAMMA * vg.y;
        o.z = sum.z - GAMMA * vg.z;
        o.w = sum.w - GAMMA * vg.w;
        *(float4*)(out + g) = o;
    } else {
        for (; g < n_out; ++g) {
            int r = g / S3;
            int j = g - r * S3;
            const float* base = slabs + (size_t)r * bpr * S3 + j;
            float sum = 0.0f;
            for (int b = 0; b < bpr; ++b) sum += base[(size_t)b * S3];
            out[g] = sum - GAMMA * v[g];
        }
    }
}

// ---------------- fallback path (no ws / too many nodes) ---------------------
__global__ void init_out_kernel(const float* __restrict__ v,
                                float* __restrict__ out, int n) {
    int i = blockIdx.x * blockDim.x + threadIdx.x;
    if (i < n) out[i] = -GAMMA * v[i];
}

__global__ void edge_atomic_kernel(const float* __restrict__ x,
                                   const int* __restrict__ src,
                                   const int* __restrict__ dst,
                                   float* __restrict__ out, int n_edges) {
    int t = blockIdx.x * blockDim.x + threadIdx.x;
    int e = t;
    if (e < n_edges) {
        int s = src[e], d = dst[e];
        float dx = x[3 * d + 0] - x[3 * s + 0];
        float dy = x[3 * d + 1] - x[3 * s + 1];
        float dz = x[3 * d + 2] - x[3 * s + 2];
        float rr = sqrtf(dx * dx + dy * dy + dz * dz);
        float inv_norm = 1.0f / fmaxf(rr, 1e-12f);
        float rc = fmaxf(rr, MIN_R);
        float s1 = 1.0f / rc;
        float s2 = s1 * s1;
        float s6 = s2 * s2 * s2;
        float F = 4.0f * s6 * (12.0f * s6 - 6.0f) * s1;
        float sc = F * inv_norm;
        unsafeAtomicAdd(&out[3 * d + 0], sc * dx);
        unsafeAtomicAdd(&out[3 * d + 1], sc * dy);
        unsafeAtomicAdd(&out[3 * d + 2], sc * dz);
    }
}

extern "C" void kernel_launch(void* const* d_in, const int* in_sizes, int n_in,
                              void* d_out, int out_size, void* d_ws, size_t ws_size,
                              hipStream_t stream) {
    const float* x   = (const float*)d_in[0];
    const float* v   = (const float*)d_in[1];
    const int*   src = (const int*)d_in[2];
    const int*   dst = (const int*)d_in[3];
    float* out = (float*)d_out;

    const int n_out = out_size;
    const int n_nodes = out_size / 3;
    const int n_edges = in_sizes[2];
    const int R = (n_nodes + NR - 1) / NR;

    // ws layout (u32 units for tables)
    const size_t counts_off  = 0;                       // NB*R
    const size_t bases_off   = (size_t)NB * R;          // NB*R
    const size_t totals_off  = 2 * (size_t)NB * R;      // R
    const size_t offsets_off = totals_off + R;          // R+1
    const size_t tables_end  = offsets_off + R + 1;
    const size_t pk_byte_off = ((tables_end * 4) + 63) & ~(size_t)63;
    const size_t slab_byte_off = ((pk_byte_off + (size_t)n_edges * 4) + 63) & ~(size_t)63;

    int bpr = 0;
    if (n_nodes <= (1 << 17) && R <= RMAX) {
        for (int cand : {16, 12, 8, 4}) {
            size_t need = slab_byte_off + (size_t)R * cand * S3 * sizeof(float);
            if (need <= ws_size) { bpr = cand; break; }
        }
    }

    if (bpr > 0) {
        unsigned* tables  = (unsigned*)d_ws;
        unsigned* counts  = tables + counts_off;
        unsigned* bases   = tables + bases_off;
        unsigned* totals  = tables + totals_off;
        unsigned* offsets = tables + offsets_off;
        unsigned* pk      = (unsigned*)((char*)d_ws + pk_byte_off);
        float*    slabs   = (float*)((char*)d_ws + slab_byte_off);

        int epb = ((n_edges + NB - 1) / NB + 3) & ~3;

        count_kernel<<<NB, THR_AC, 0, stream>>>(dst, counts, n_edges, epb, R);
        scan_blocks_kernel<<<R, NB, 0, stream>>>(counts, bases, totals, R);
        scan_bins_kernel<<<1, RMAX, 0, stream>>>(totals, offsets, R);
        scatter_kernel<<<NB, THR_AC, 0, stream>>>(src, dst, bases, offsets, pk,
                                                  n_edges, epb, R);
        dim3 gridD(bpr, R);
        process_kernel<<<gridD, THR_D, 0, stream>>>(x, pk, offsets, slabs,
                                                    n_nodes, bpr);
        int n4 = (n_out + 3) / 4;
        merge_kernel<<<(n4 + 255) / 256, 256, 0, stream>>>(slabs, v, out,
                                                           n_out, bpr);
    } else {
        int blk = 256;
        init_out_kernel<<<(n_out + blk - 1) / blk, blk, 0, stream>>>(v, out, n_out);
        edge_atomic_kernel<<<(n_edges + blk - 1) / blk, blk, 0, stream>>>(
            x, src, dst, out, n_edges);
    }
}